// Round 9
// baseline (307.643 us; speedup 1.0000x reference)
//
#include <hip/hip_runtime.h>
#include <math.h>

#define Bq 8
#define Sq 2048
#define Hq 1024
#define QT 8           // attn rows per block (4 waves x 2 rows) -> 2048 blocks
#define INV_SQRT_H (1.0f / 32.0f)

typedef float f32x4 __attribute__((ext_vector_type(4)));

__device__ __forceinline__ float waveReduceSum(float v) {
#pragma unroll
    for (int off = 32; off > 0; off >>= 1) v += __shfl_xor(v, off, 64);
    return v;
}

// ---------------------------------------------------------------------------
// prep: blocks 0..255  -> wq_eff[h] = sum_o Wq[o,h]*Wk[o]  (atomic o-chunks)
//       block  256     -> cb = (bq . Wk)/sqrt(H)
//       blocks 257..264-> per-batch min/max of sqi
// ---------------------------------------------------------------------------
__global__ void k_prep(const float* __restrict__ Wq, const float* __restrict__ Wk,
                       const float* __restrict__ bq, const float* __restrict__ sqi,
                       float* __restrict__ wq_eff, float* __restrict__ cb,
                       float* __restrict__ ext) {
    int bid = blockIdx.x, t = threadIdx.x;
    int wid = t >> 6, lane = t & 63;
    if (bid < 256) {
        int hc = bid & 3, oc = bid >> 2;       // 4 h-chunks x 64 o-chunks
        int h = hc * 256 + t, o0 = oc * 16;
        float acc = 0.f;
#pragma unroll
        for (int o = 0; o < 16; ++o)
            acc += Wq[(size_t)(o0 + o) * Hq + h] * Wk[o0 + o];
        atomicAdd(&wq_eff[h], acc);
    } else if (bid == 256) {
        float acc = 0.f;
#pragma unroll
        for (int j = 0; j < 4; ++j) acc += bq[t * 4 + j] * Wk[t * 4 + j];
        acc = waveReduceSum(acc);
        __shared__ float red[4];
        if (lane == 0) red[wid] = acc;
        __syncthreads();
        if (t == 0) *cb = (red[0] + red[1] + red[2] + red[3]) * INV_SQRT_H;
    } else {
        int b = bid - 257;
        float mn = 1e30f, mx = -1e30f;
        for (int j = t; j < Sq; j += 256) {
            float v = sqi[b * Sq + j];
            mn = fminf(mn, v);
            mx = fmaxf(mx, v);
        }
#pragma unroll
        for (int off = 32; off > 0; off >>= 1) {
            mn = fminf(mn, __shfl_xor(mn, off, 64));
            mx = fmaxf(mx, __shfl_xor(mx, off, 64));
        }
        __shared__ float smn[4], smx[4];
        if (lane == 0) { smn[wid] = mn; smx[wid] = mx; }
        __syncthreads();
        if (t == 0) {
            ext[b]      = fminf(fminf(smn[0], smn[1]), fminf(smn[2], smn[3]));
            ext[Bq + b] = fmaxf(fmaxf(smx[0], smx[1]), fmaxf(smx[2], smx[3]));
        }
    }
}

// attn[b,q,:] = softmax( a[b,q]*sqi[b,:] ); a = ((hid+pos).wq_eff)/32 + cb.
// Wave owns 2 rows; 2048 blocks -> 8 blocks/CU for latency hiding.
__global__ void __launch_bounds__(256) k_attn(
        const float* __restrict__ hidden, const float* __restrict__ pos,
        const float* __restrict__ wq_eff, const float* __restrict__ cbp,
        const float* __restrict__ sqi, const float* __restrict__ ext,
        float* __restrict__ attn, float* __restrict__ wcol) {
    int b = blockIdx.y, qt = blockIdx.x, t = threadIdx.x;
    int wid = t >> 6, lane = t & 63;
    __shared__ float sqi_s[Sq];
    __shared__ float colsum[Sq];
    {
        const float4* sp = (const float4*)(sqi + b * Sq);
        float4* ds = (float4*)sqi_s;
        ds[t]       = sp[t];
        ds[256 + t] = sp[256 + t];
        float4* cz = (float4*)colsum;
        cz[t]       = make_float4(0.f, 0.f, 0.f, 0.f);
        cz[256 + t] = make_float4(0.f, 0.f, 0.f, 0.f);
    }
    float smin = ext[b], smax = ext[Bq + b];
    float cbv = *cbp;

    // ---- a-phase: wave computes a for its 2 rows ((hid+pos).wq_eff)/32 + cb
    const float4* wp = (const float4*)wq_eff;
    float4 w0 = wp[lane], w1 = wp[lane + 64], w2 = wp[lane + 128], w3 = wp[lane + 192];
    int q0 = qt * QT + wid * 2;
    float a[2];
#pragma unroll
    for (int r = 0; r < 2; ++r) {
        const float4* hp = (const float4*)(hidden + (size_t)(b * Sq + q0 + r) * Hq);
        const float4* pp = (const float4*)(pos + (size_t)(q0 + r) * Hq);
        float4 h0 = hp[lane], h1 = hp[lane + 64], h2 = hp[lane + 128], h3 = hp[lane + 192];
        float4 p0 = pp[lane], p1 = pp[lane + 64], p2 = pp[lane + 128], p3 = pp[lane + 192];
        float d = (h0.x + p0.x) * w0.x + (h0.y + p0.y) * w0.y + (h0.z + p0.z) * w0.z + (h0.w + p0.w) * w0.w
                + (h1.x + p1.x) * w1.x + (h1.y + p1.y) * w1.y + (h1.z + p1.z) * w1.z + (h1.w + p1.w) * w1.w
                + (h2.x + p2.x) * w2.x + (h2.y + p2.y) * w2.y + (h2.z + p2.z) * w2.z + (h2.w + p2.w) * w2.w
                + (h3.x + p3.x) * w3.x + (h3.y + p3.y) * w3.y + (h3.z + p3.z) * w3.z + (h3.w + p3.w) * w3.w;
        d = waveReduceSum(d);
        a[r] = d * INV_SQRT_H + cbv;
    }
    __syncthreads();   // sqi_s + zeroed colsum ready

    // ---- softmax phase: per row, lane covers 8 float4 chunks (32 cols)
    const float4* ss = (const float4*)sqi_s;
    float4 ca[8];
#pragma unroll
    for (int c = 0; c < 8; ++c) ca[c] = make_float4(0.f, 0.f, 0.f, 0.f);

#pragma unroll
    for (int r = 0; r < 2; ++r) {
        float aa = a[r];
        float m = (aa > 0.f) ? aa * smax : aa * smin;   // exact row max
        float4 e[8];
        float s = 0.f;
#pragma unroll
        for (int c = 0; c < 8; ++c) {
            float4 sv = ss[lane + 64 * c];
            e[c].x = __expf(aa * sv.x - m);
            e[c].y = __expf(aa * sv.y - m);
            e[c].z = __expf(aa * sv.z - m);
            e[c].w = __expf(aa * sv.w - m);
            s += e[c].x + e[c].y + e[c].z + e[c].w;
        }
        s = waveReduceSum(s);
        float rinv = 1.0f / s;
        f32x4* orow = (f32x4*)(attn + (size_t)(b * Sq + q0 + r) * Sq);
#pragma unroll
        for (int c = 0; c < 8; ++c) {
            f32x4 p;
            p.x = e[c].x * rinv; p.y = e[c].y * rinv;
            p.z = e[c].z * rinv; p.w = e[c].w * rinv;
            __builtin_nontemporal_store(p, &orow[lane + 64 * c]);
            ca[c].x += p.x; ca[c].y += p.y; ca[c].z += p.z; ca[c].w += p.w;
        }
    }

    // ---- column-sum combine: LDS atomics (ds_add_f32), then global atomics
#pragma unroll
    for (int c = 0; c < 8; ++c) {
        int base = (lane + 64 * c) * 4;
        atomicAdd(&colsum[base + 0], ca[c].x);
        atomicAdd(&colsum[base + 1], ca[c].y);
        atomicAdd(&colsum[base + 2], ca[c].z);
        atomicAdd(&colsum[base + 3], ca[c].w);
    }
    __syncthreads();
#pragma unroll
    for (int j = 0; j < 8; ++j)
        atomicAdd(&wcol[b * Sq + j * 256 + t], colsum[j * 256 + t]);
}

// y[b,h] = sum_kk (wcol[b,kk]/S) * (hidden[b,kk,h] + pos[kk,h])
__global__ void k_y(const float* __restrict__ hidden, const float* __restrict__ pos,
                    const float* __restrict__ wcol, float* __restrict__ y) {
    int b = blockIdx.y, kc = blockIdx.x, t = threadIdx.x;
    int kk0 = kc * 32;             // 32 rows per block, 64 blocks per batch
    float4 acc = {0, 0, 0, 0};
#pragma unroll 8
    for (int i = 0; i < 32; ++i) {
        int kk = kk0 + i;
        float wv = wcol[b * Sq + kk] * (1.0f / Sq);
        float4 hv = ((const float4*)(hidden + ((size_t)(b * Sq + kk)) * Hq))[t];
        float4 pv = ((const float4*)(pos + (size_t)kk * Hq))[t];
        acc.x += wv * (hv.x + pv.x);
        acc.y += wv * (hv.y + pv.y);
        acc.z += wv * (hv.z + pv.z);
        acc.w += wv * (hv.w + pv.w);
    }
    atomicAdd(&y[b * Hq + t * 4 + 0], acc.x);
    atomicAdd(&y[b * Hq + t * 4 + 1], acc.y);
    atomicAdd(&y[b * Hq + t * 4 + 2], acc.z);
    atomicAdd(&y[b * Hq + t * 4 + 3], acc.w);
}

// ctx[b,h] = Wv[h,:] . y[b,:] + bv[h]  -- wave per 4 rows, direct store
__global__ void k_ctx(const float* __restrict__ Wv, const float* __restrict__ bv,
                      const float* __restrict__ y, float* __restrict__ ctx) {
    int b = blockIdx.y, t = threadIdx.x;
    int wid = t >> 6, lane = t & 63;
    __shared__ float4 ys4[Hq / 4];
    ys4[t] = ((const float4*)(y + b * Hq))[t];
    __syncthreads();
    float4 y0 = ys4[lane], y1 = ys4[lane + 64], y2 = ys4[lane + 128], y3 = ys4[lane + 192];
    int h0 = blockIdx.x * 16 + wid * 4;
#pragma unroll
    for (int r = 0; r < 4; ++r) {
        int h = h0 + r;
        const float4* wrow = (const float4*)(Wv + (size_t)h * Hq);
        float4 v0 = wrow[lane], v1 = wrow[lane + 64], v2 = wrow[lane + 128], v3 = wrow[lane + 192];
        float d = v0.x * y0.x + v0.y * y0.y + v0.z * y0.z + v0.w * y0.w
                + v1.x * y1.x + v1.y * y1.y + v1.z * y1.z + v1.w * y1.w
                + v2.x * y2.x + v2.y * y2.y + v2.z * y2.z + v2.w * y2.w
                + v3.x * y3.x + v3.y * y3.y + v3.z * y3.z + v3.w * y3.w;
        d = waveReduceSum(d);
        if (lane == 0) ctx[b * Hq + h] = d + bv[h];
    }
}

extern "C" void kernel_launch(void* const* d_in, const int* in_sizes, int n_in,
                              void* d_out, int out_size, void* d_ws, size_t ws_size,
                              hipStream_t stream) {
    const float* hidden = (const float*)d_in[0];
    const float* sqi    = (const float*)d_in[1];
    const float* pos    = (const float*)d_in[2];
    const float* Wq     = (const float*)d_in[3];
    const float* bq     = (const float*)d_in[4];
    const float* Wk     = (const float*)d_in[5];
    // bk (d_in[6]) shifts every score in a row equally -> cancels in softmax
    const float* Wv     = (const float*)d_in[7];
    const float* bv     = (const float*)d_in[8];

    float* out  = (float*)d_out;
    float* ctx  = out;                    // [B,H]
    float* attn = out + Bq * Hq;          // [B,S,S]

    // workspace layout (floats)
    float* ws     = (float*)d_ws;
    float* wq_eff = ws;                   // 1024
    float* wcol   = ws + 1024;            // 16384
    float* y      = ws + 17408;           // 8192   (zeroed region ends: 25600)
    float* ext    = ws + 25600;           // 16 (min[8], max[8])
    float* cb     = ws + 25616;           // 1

    (void)hipMemsetAsync(ws, 0, 25600 * sizeof(float), stream);    // wq_eff+wcol+y

    k_prep<<<265, 256, 0, stream>>>(Wq, Wk, bq, sqi, wq_eff, cb, ext);
    k_attn<<<dim3(Sq / QT, Bq), 256, 0, stream>>>(hidden, pos, wq_eff, cb,
                                                  sqi, ext, attn, wcol);
    k_y   <<<dim3(64, Bq), 256, 0, stream>>>(hidden, pos, wcol, y);
    k_ctx <<<dim3(Hq / 16, Bq), 256, 0, stream>>>(Wv, bv, y, ctx);
}

// Round 10
// 259.379 us; speedup vs baseline: 1.1861x; 1.1861x over previous
//
#include <hip/hip_runtime.h>
#include <math.h>

#define Bq 8
#define Sq 2048
#define Hq 1024
#define QT 16          // attn rows per block in k_attn_w (4 waves x 4 rows)
#define INV_SQRT_H (1.0f / 32.0f)

typedef float f32x4 __attribute__((ext_vector_type(4)));

__device__ __forceinline__ float waveReduceSum(float v) {
#pragma unroll
    for (int off = 32; off > 0; off >>= 1) v += __shfl_xor(v, off, 64);
    return v;
}

// branchless exact row max of a*sqi over the batch row (sqi in [smin,smax])
__device__ __forceinline__ float rowMax(float aa, float smin, float smax) {
    return fmaxf(aa * smax, aa * smin);
}

// ---------------------------------------------------------------------------
// prep: blocks 0..255  -> wq_eff[h] = sum_o Wq[o,h]*Wk[o]  (atomic o-chunks)
//       block  256     -> cb = (bq . Wk)/sqrt(H)
//       blocks 257..264-> per-batch min/max of sqi
// ---------------------------------------------------------------------------
__global__ void k_prep(const float* __restrict__ Wq, const float* __restrict__ Wk,
                       const float* __restrict__ bq, const float* __restrict__ sqi,
                       float* __restrict__ wq_eff, float* __restrict__ cb,
                       float* __restrict__ ext) {
    int bid = blockIdx.x, t = threadIdx.x;
    int wid = t >> 6, lane = t & 63;
    if (bid < 256) {
        int hc = bid & 3, oc = bid >> 2;       // 4 h-chunks x 64 o-chunks
        int h = hc * 256 + t, o0 = oc * 16;
        float acc = 0.f;
#pragma unroll
        for (int o = 0; o < 16; ++o)
            acc += Wq[(size_t)(o0 + o) * Hq + h] * Wk[o0 + o];
        atomicAdd(&wq_eff[h], acc);
    } else if (bid == 256) {
        float acc = 0.f;
#pragma unroll
        for (int j = 0; j < 4; ++j) acc += bq[t * 4 + j] * Wk[t * 4 + j];
        acc = waveReduceSum(acc);
        __shared__ float red[4];
        if (lane == 0) red[wid] = acc;
        __syncthreads();
        if (t == 0) *cb = (red[0] + red[1] + red[2] + red[3]) * INV_SQRT_H;
    } else {
        int b = bid - 257;
        float mn = 1e30f, mx = -1e30f;
        for (int j = t; j < Sq; j += 256) {
            float v = sqi[b * Sq + j];
            mn = fminf(mn, v);
            mx = fmaxf(mx, v);
        }
#pragma unroll
        for (int off = 32; off > 0; off >>= 1) {
            mn = fminf(mn, __shfl_xor(mn, off, 64));
            mx = fmaxf(mx, __shfl_xor(mx, off, 64));
        }
        __shared__ float smn[4], smx[4];
        if (lane == 0) { smn[wid] = mn; smx[wid] = mx; }
        __syncthreads();
        if (t == 0) {
            ext[b]      = fminf(fminf(smn[0], smn[1]), fminf(smn[2], smn[3]));
            ext[Bq + b] = fmaxf(fmaxf(smx[0], smx[1]), fmaxf(smx[2], smx[3]));
        }
    }
}

// a[b,q] = ((hid+pos).wq_eff)/32 + cb ;  rinv[b,q] = 1/sum_kk exp(a*sqi-m)
// wave per row, 4 rows/block, 4096 blocks
__global__ void __launch_bounds__(256) k_a(
        const float* __restrict__ hidden, const float* __restrict__ pos,
        const float* __restrict__ wq_eff, const float* __restrict__ cbp,
        const float* __restrict__ sqi, const float* __restrict__ ext,
        float* __restrict__ a_arr, float* __restrict__ rinv_arr) {
    int b = blockIdx.y, t = threadIdx.x;
    int wid = t >> 6, lane = t & 63;
    __shared__ float sqi_s[Sq];
    {
        const float4* sp = (const float4*)(sqi + b * Sq);
        float4* ds = (float4*)sqi_s;
        ds[t]       = sp[t];
        ds[256 + t] = sp[256 + t];
    }
    float smin = ext[b], smax = ext[Bq + b];
    float cbv = *cbp;

    int q = blockIdx.x * 4 + wid;
    const float4* hp = (const float4*)(hidden + (size_t)(b * Sq + q) * Hq);
    const float4* pp = (const float4*)(pos + (size_t)q * Hq);
    const float4* wp = (const float4*)wq_eff;
    float d = 0.f;
#pragma unroll
    for (int seg = 0; seg < 4; ++seg) {
        float4 h = hp[lane + 64 * seg];
        float4 p = pp[lane + 64 * seg];
        float4 w = wp[lane + 64 * seg];
        d += (h.x + p.x) * w.x + (h.y + p.y) * w.y +
             (h.z + p.z) * w.z + (h.w + p.w) * w.w;
    }
    d = waveReduceSum(d);
    float aa = d * INV_SQRT_H + cbv;       // all lanes hold aa after reduce
    float m = rowMax(aa, smin, smax);
    __syncthreads();                        // sqi_s ready

    const float4* ss = (const float4*)sqi_s;
    float s = 0.f;
#pragma unroll
    for (int c = 0; c < 8; ++c) {
        float4 sv = ss[lane + 64 * c];
        s += __expf(aa * sv.x - m) + __expf(aa * sv.y - m)
           + __expf(aa * sv.z - m) + __expf(aa * sv.w - m);
    }
    s = waveReduceSum(s);
    if (lane == 0) {
        a_arr[b * Sq + q]    = aa;
        rinv_arr[b * Sq + q] = 1.0f / s;
    }
}

// wcol[b,kk] = sum_q rinv[q]*exp(a[q]*sqi[kk]-m[q]); thread owns one column,
// q split into 4 chunks of 512 (one atomic per thread). Bitwise-same __expf
// formula as k_attn_w -> consistent with written attn.
__global__ void __launch_bounds__(256) k_wcol(
        const float* __restrict__ sqi, const float* __restrict__ a_arr,
        const float* __restrict__ rinv_arr, const float* __restrict__ ext,
        float* __restrict__ wcol) {
    int b = blockIdx.y;
    int kt = blockIdx.x >> 2;      // 8 column tiles of 256
    int qc = blockIdx.x & 3;       // 4 q chunks of 512
    int t = threadIdx.x;
    __shared__ float a_s[512], r_s[512];
    int qbase = qc * 512;
    a_s[t]       = a_arr[b * Sq + qbase + t];
    a_s[256 + t] = a_arr[b * Sq + qbase + 256 + t];
    r_s[t]       = rinv_arr[b * Sq + qbase + t];
    r_s[256 + t] = rinv_arr[b * Sq + qbase + 256 + t];
    float smin = ext[b], smax = ext[Bq + b];
    int kk = kt * 256 + t;
    float sk = sqi[b * Sq + kk];
    __syncthreads();
    float acc = 0.f;
#pragma unroll 4
    for (int j = 0; j < 512; ++j) {
        float aa = a_s[j];                    // LDS broadcast (conflict-free)
        float m = rowMax(aa, smin, smax);
        acc += r_s[j] * __expf(aa * sk - m);
    }
    atomicAdd(&wcol[b * Sq + kk], acc);
}

// attn[b,q,:] = exp(a*sqi - m) * rinv  -- pure streaming write, no tail.
__global__ void __launch_bounds__(256) k_attn_w(
        const float* __restrict__ sqi, const float* __restrict__ a_arr,
        const float* __restrict__ rinv_arr, const float* __restrict__ ext,
        float* __restrict__ attn) {
    int b = blockIdx.y, qt = blockIdx.x, t = threadIdx.x;
    int wid = t >> 6, lane = t & 63;
    __shared__ float sqi_s[Sq];
    {
        const float4* sp = (const float4*)(sqi + b * Sq);
        float4* ds = (float4*)sqi_s;
        ds[t]       = sp[t];
        ds[256 + t] = sp[256 + t];
    }
    float smin = ext[b], smax = ext[Bq + b];
    __syncthreads();

    const float4* ss = (const float4*)sqi_s;
    int q0 = qt * QT + wid * (QT / 4);
#pragma unroll
    for (int r = 0; r < QT / 4; ++r) {
        int q = q0 + r;
        float aa = a_arr[b * Sq + q];         // wave-uniform broadcast load
        float rv = rinv_arr[b * Sq + q];
        float m = rowMax(aa, smin, smax);
        f32x4* orow = (f32x4*)(attn + (size_t)(b * Sq + q) * Sq);
#pragma unroll
        for (int c = 0; c < 8; ++c) {
            float4 sv = ss[lane + 64 * c];
            f32x4 p;
            p.x = __expf(aa * sv.x - m) * rv;
            p.y = __expf(aa * sv.y - m) * rv;
            p.z = __expf(aa * sv.z - m) * rv;
            p.w = __expf(aa * sv.w - m) * rv;
            __builtin_nontemporal_store(p, &orow[lane + 64 * c]);
        }
    }
}

// y[b,h] = sum_kk (wcol[b,kk]/S) * (hidden[b,kk,h] + pos[kk,h])
__global__ void k_y(const float* __restrict__ hidden, const float* __restrict__ pos,
                    const float* __restrict__ wcol, float* __restrict__ y) {
    int b = blockIdx.y, kc = blockIdx.x, t = threadIdx.x;
    int kk0 = kc * 32;             // 32 rows per block, 64 blocks per batch
    float4 acc = {0, 0, 0, 0};
#pragma unroll 8
    for (int i = 0; i < 32; ++i) {
        int kk = kk0 + i;
        float wv = wcol[b * Sq + kk] * (1.0f / Sq);
        float4 hv = ((const float4*)(hidden + ((size_t)(b * Sq + kk)) * Hq))[t];
        float4 pv = ((const float4*)(pos + (size_t)kk * Hq))[t];
        acc.x += wv * (hv.x + pv.x);
        acc.y += wv * (hv.y + pv.y);
        acc.z += wv * (hv.z + pv.z);
        acc.w += wv * (hv.w + pv.w);
    }
    atomicAdd(&y[b * Hq + t * 4 + 0], acc.x);
    atomicAdd(&y[b * Hq + t * 4 + 1], acc.y);
    atomicAdd(&y[b * Hq + t * 4 + 2], acc.z);
    atomicAdd(&y[b * Hq + t * 4 + 3], acc.w);
}

// ctx[b,h] = Wv[h,:] . y[b,:] + bv[h]  -- wave per 4 rows, direct store
__global__ void k_ctx(const float* __restrict__ Wv, const float* __restrict__ bv,
                      const float* __restrict__ y, float* __restrict__ ctx) {
    int b = blockIdx.y, t = threadIdx.x;
    int wid = t >> 6, lane = t & 63;
    __shared__ float4 ys4[Hq / 4];
    ys4[t] = ((const float4*)(y + b * Hq))[t];
    __syncthreads();
    float4 y0 = ys4[lane], y1 = ys4[lane + 64], y2 = ys4[lane + 128], y3 = ys4[lane + 192];
    int h0 = blockIdx.x * 16 + wid * 4;
#pragma unroll
    for (int r = 0; r < 4; ++r) {
        int h = h0 + r;
        const float4* wrow = (const float4*)(Wv + (size_t)h * Hq);
        float4 v0 = wrow[lane], v1 = wrow[lane + 64], v2 = wrow[lane + 128], v3 = wrow[lane + 192];
        float d = v0.x * y0.x + v0.y * y0.y + v0.z * y0.z + v0.w * y0.w
                + v1.x * y1.x + v1.y * y1.y + v1.z * y1.z + v1.w * y1.w
                + v2.x * y2.x + v2.y * y2.y + v2.z * y2.z + v2.w * y2.w
                + v3.x * y3.x + v3.y * y3.y + v3.z * y3.z + v3.w * y3.w;
        d = waveReduceSum(d);
        if (lane == 0) ctx[b * Hq + h] = d + bv[h];
    }
}

extern "C" void kernel_launch(void* const* d_in, const int* in_sizes, int n_in,
                              void* d_out, int out_size, void* d_ws, size_t ws_size,
                              hipStream_t stream) {
    const float* hidden = (const float*)d_in[0];
    const float* sqi    = (const float*)d_in[1];
    const float* pos    = (const float*)d_in[2];
    const float* Wq     = (const float*)d_in[3];
    const float* bq     = (const float*)d_in[4];
    const float* Wk     = (const float*)d_in[5];
    // bk (d_in[6]) shifts every score in a row equally -> cancels in softmax
    const float* Wv     = (const float*)d_in[7];
    const float* bv     = (const float*)d_in[8];

    float* out  = (float*)d_out;
    float* ctx  = out;                    // [B,H]
    float* attn = out + Bq * Hq;          // [B,S,S]

    // workspace layout (floats)
    float* ws       = (float*)d_ws;
    float* wq_eff   = ws;                 // 1024
    float* wcol     = ws + 1024;          // 16384
    float* y        = ws + 17408;         // 8192  (zeroed region ends: 25600)
    float* ext      = ws + 25600;         // 16 (min[8], max[8])
    float* cb       = ws + 25616;         // 1
    float* a_arr    = ws + 25632;         // 16384
    float* rinv_arr = ws + 42016;         // 16384

    (void)hipMemsetAsync(ws, 0, 25600 * sizeof(float), stream);   // wq_eff+wcol+y

    k_prep  <<<265, 256, 0, stream>>>(Wq, Wk, bq, sqi, wq_eff, cb, ext);
    k_a     <<<dim3(Sq / 4, Bq), 256, 0, stream>>>(hidden, pos, wq_eff, cb,
                                                   sqi, ext, a_arr, rinv_arr);
    k_wcol  <<<dim3(32, Bq), 256, 0, stream>>>(sqi, a_arr, rinv_arr, ext, wcol);
    k_attn_w<<<dim3(Sq / QT, Bq), 256, 0, stream>>>(sqi, a_arr, rinv_arr, ext, attn);
    k_y     <<<dim3(64, Bq), 256, 0, stream>>>(hidden, pos, wcol, y);
    k_ctx   <<<dim3(Hq / 16, Bq), 256, 0, stream>>>(Wv, bv, y, ctx);
}

// Round 11
// 250.409 us; speedup vs baseline: 1.2286x; 1.0358x over previous
//
#include <hip/hip_runtime.h>
#include <math.h>

#define Bq 8
#define Sq 2048
#define Hq 1024
#define QT 16          // attn rows per block in k_attn_w (4 waves x 4 rows)
#define INV_SQRT_H (1.0f / 32.0f)

typedef float f32x4 __attribute__((ext_vector_type(4)));

__device__ __forceinline__ float waveReduceSum(float v) {
#pragma unroll
    for (int off = 32; off > 0; off >>= 1) v += __shfl_xor(v, off, 64);
    return v;
}

// branchless exact row max of a*sqi over the batch row (sqi in [smin,smax])
__device__ __forceinline__ float rowMax(float aa, float smin, float smax) {
    return fmaxf(aa * smax, aa * smin);
}

// ---------------------------------------------------------------------------
// prep: blocks 0..255  -> wq_eff[h] = sum_o Wq[o,h]*Wk[o]  (atomic o-chunks)
//       block  256     -> cb = (bq . Wk)/sqrt(H)
//       blocks 257..264-> per-batch min/max of sqi
// ---------------------------------------------------------------------------
__global__ void k_prep(const float* __restrict__ Wq, const float* __restrict__ Wk,
                       const float* __restrict__ bq, const float* __restrict__ sqi,
                       float* __restrict__ wq_eff, float* __restrict__ cb,
                       float* __restrict__ ext) {
    int bid = blockIdx.x, t = threadIdx.x;
    int wid = t >> 6, lane = t & 63;
    if (bid < 256) {
        int hc = bid & 3, oc = bid >> 2;       // 4 h-chunks x 64 o-chunks
        int h = hc * 256 + t, o0 = oc * 16;
        float acc = 0.f;
#pragma unroll
        for (int o = 0; o < 16; ++o)
            acc += Wq[(size_t)(o0 + o) * Hq + h] * Wk[o0 + o];
        atomicAdd(&wq_eff[h], acc);
    } else if (bid == 256) {
        float acc = 0.f;
#pragma unroll
        for (int j = 0; j < 4; ++j) acc += bq[t * 4 + j] * Wk[t * 4 + j];
        acc = waveReduceSum(acc);
        __shared__ float red[4];
        if (lane == 0) red[wid] = acc;
        __syncthreads();
        if (t == 0) *cb = (red[0] + red[1] + red[2] + red[3]) * INV_SQRT_H;
    } else {
        int b = bid - 257;
        float mn = 1e30f, mx = -1e30f;
        for (int j = t; j < Sq; j += 256) {
            float v = sqi[b * Sq + j];
            mn = fminf(mn, v);
            mx = fmaxf(mx, v);
        }
#pragma unroll
        for (int off = 32; off > 0; off >>= 1) {
            mn = fminf(mn, __shfl_xor(mn, off, 64));
            mx = fmaxf(mx, __shfl_xor(mx, off, 64));
        }
        __shared__ float smn[4], smx[4];
        if (lane == 0) { smn[wid] = mn; smx[wid] = mx; }
        __syncthreads();
        if (t == 0) {
            ext[b]      = fminf(fminf(smn[0], smn[1]), fminf(smn[2], smn[3]));
            ext[Bq + b] = fmaxf(fmaxf(smx[0], smx[1]), fmaxf(smx[2], smx[3]));
        }
    }
}

// a[b,q] = ((hid+pos).wq_eff)/32 + cb ;  rinv[b,q] = 1/sum_kk exp(a*sqi-m)
// wave per row, 4 rows/block, 4096 blocks
__global__ void __launch_bounds__(256) k_a(
        const float* __restrict__ hidden, const float* __restrict__ pos,
        const float* __restrict__ wq_eff, const float* __restrict__ cbp,
        const float* __restrict__ sqi, const float* __restrict__ ext,
        float* __restrict__ a_arr, float* __restrict__ rinv_arr) {
    int b = blockIdx.y, t = threadIdx.x;
    int wid = t >> 6, lane = t & 63;
    __shared__ float sqi_s[Sq];
    {
        const float4* sp = (const float4*)(sqi + b * Sq);
        float4* ds = (float4*)sqi_s;
        ds[t]       = sp[t];
        ds[256 + t] = sp[256 + t];
    }
    float smin = ext[b], smax = ext[Bq + b];
    float cbv = *cbp;

    int q = blockIdx.x * 4 + wid;
    const float4* hp = (const float4*)(hidden + (size_t)(b * Sq + q) * Hq);
    const float4* pp = (const float4*)(pos + (size_t)q * Hq);
    const float4* wp = (const float4*)wq_eff;
    float d = 0.f;
#pragma unroll
    for (int seg = 0; seg < 4; ++seg) {
        float4 h = hp[lane + 64 * seg];
        float4 p = pp[lane + 64 * seg];
        float4 w = wp[lane + 64 * seg];
        d += (h.x + p.x) * w.x + (h.y + p.y) * w.y +
             (h.z + p.z) * w.z + (h.w + p.w) * w.w;
    }
    d = waveReduceSum(d);
    float aa = d * INV_SQRT_H + cbv;       // all lanes hold aa after reduce
    float m = rowMax(aa, smin, smax);
    __syncthreads();                        // sqi_s ready

    const float4* ss = (const float4*)sqi_s;
    float s = 0.f;
#pragma unroll
    for (int c = 0; c < 8; ++c) {
        float4 sv = ss[lane + 64 * c];
        s += __expf(aa * sv.x - m) + __expf(aa * sv.y - m)
           + __expf(aa * sv.z - m) + __expf(aa * sv.w - m);
    }
    s = waveReduceSum(s);
    if (lane == 0) {
        a_arr[b * Sq + q]    = aa;
        rinv_arr[b * Sq + q] = 1.0f / s;
    }
}

// attn[b,q,:] = exp(a*sqi - m) * rinv  -- pure streaming write, no tail.
__global__ void __launch_bounds__(256) k_attn_w(
        const float* __restrict__ sqi, const float* __restrict__ a_arr,
        const float* __restrict__ rinv_arr, const float* __restrict__ ext,
        float* __restrict__ attn) {
    int b = blockIdx.y, qt = blockIdx.x, t = threadIdx.x;
    int wid = t >> 6, lane = t & 63;
    __shared__ float sqi_s[Sq];
    {
        const float4* sp = (const float4*)(sqi + b * Sq);
        float4* ds = (float4*)sqi_s;
        ds[t]       = sp[t];
        ds[256 + t] = sp[256 + t];
    }
    float smin = ext[b], smax = ext[Bq + b];
    __syncthreads();

    const float4* ss = (const float4*)sqi_s;
    int q0 = qt * QT + wid * (QT / 4);
    float av[QT / 4], rv[QT / 4];
#pragma unroll
    for (int r = 0; r < QT / 4; ++r) {      // hoist row scalars (broadcast loads)
        av[r] = a_arr[b * Sq + q0 + r];
        rv[r] = rinv_arr[b * Sq + q0 + r];
    }
#pragma unroll
    for (int r = 0; r < QT / 4; ++r) {
        float aa = av[r];
        float rvv = rv[r];
        float m = rowMax(aa, smin, smax);
        f32x4* orow = (f32x4*)(attn + (size_t)(b * Sq + q0 + r) * Sq);
#pragma unroll
        for (int c = 0; c < 8; ++c) {
            float4 sv = ss[lane + 64 * c];
            f32x4 p;
            p.x = __expf(aa * sv.x - m) * rvv;
            p.y = __expf(aa * sv.y - m) * rvv;
            p.z = __expf(aa * sv.z - m) * rvv;
            p.w = __expf(aa * sv.w - m) * rvv;
            __builtin_nontemporal_store(p, &orow[lane + 64 * c]);
        }
    }
}

// Fused column-weights + y accumulation.
// Block (kc,b) owns 32 columns: wv[c] = (1/S) sum_q rinv[q]*exp(a[q]*sqi[c]-m[q])
// computed locally (bitwise-same expf formula as k_attn_w), then
// y[b,h] += sum_{kk in tile} wv * (hidden[b,kk,h] + pos[kk,h]).
__global__ void __launch_bounds__(256) k_yw(
        const float* __restrict__ hidden, const float* __restrict__ pos,
        const float* __restrict__ sqi, const float* __restrict__ a_arr,
        const float* __restrict__ rinv_arr, const float* __restrict__ ext,
        float* __restrict__ y) {
    int b = blockIdx.y, kc = blockIdx.x, t = threadIdx.x;
    __shared__ float a_s[Sq], r_s[Sq];
    __shared__ float partial[32][9];        // 9 (coprime 32) -> conflict-free
    __shared__ float wv_s[32];
    {
        const float4* ap = (const float4*)(a_arr + b * Sq);
        const float4* rp = (const float4*)(rinv_arr + b * Sq);
        float4* as4 = (float4*)a_s;
        float4* rs4 = (float4*)r_s;
        as4[t] = ap[t];  as4[256 + t] = ap[256 + t];
        rs4[t] = rp[t];  rs4[256 + t] = rp[256 + t];
    }
    float smin = ext[b], smax = ext[Bq + b];
    int c = t & 31, chunk = t >> 5;        // 32 cols x 8 q-chunks of 256
    int kk0 = kc * 32;
    float sk = sqi[b * Sq + kk0 + c];
    __syncthreads();

    float acc = 0.f;
    int j0 = chunk * 256;
#pragma unroll 8
    for (int j = 0; j < 256; ++j) {
        float aa = a_s[j0 + j];            // 2-addr broadcast per wave (free)
        float m = rowMax(aa, smin, smax);
        acc += r_s[j0 + j] * __expf(aa * sk - m);
    }
    partial[c][chunk] = acc;
    __syncthreads();
    if (t < 32) {
        float w = 0.f;
#pragma unroll
        for (int u = 0; u < 8; ++u) w += partial[t][u];
        wv_s[t] = w * (1.0f / Sq);
    }
    __syncthreads();

    float4 accv = {0, 0, 0, 0};
#pragma unroll 8
    for (int i = 0; i < 32; ++i) {
        int kk = kk0 + i;
        float wv = wv_s[i];
        float4 hv = ((const float4*)(hidden + ((size_t)(b * Sq + kk)) * Hq))[t];
        float4 pv = ((const float4*)(pos + (size_t)kk * Hq))[t];
        accv.x += wv * (hv.x + pv.x);
        accv.y += wv * (hv.y + pv.y);
        accv.z += wv * (hv.z + pv.z);
        accv.w += wv * (hv.w + pv.w);
    }
    atomicAdd(&y[b * Hq + t * 4 + 0], accv.x);
    atomicAdd(&y[b * Hq + t * 4 + 1], accv.y);
    atomicAdd(&y[b * Hq + t * 4 + 2], accv.z);
    atomicAdd(&y[b * Hq + t * 4 + 3], accv.w);
}

// ctx[b,h] = Wv[h,:] . y[b,:] + bv[h]  -- wave per 4 rows, direct store
__global__ void k_ctx(const float* __restrict__ Wv, const float* __restrict__ bv,
                      const float* __restrict__ y, float* __restrict__ ctx) {
    int b = blockIdx.y, t = threadIdx.x;
    int wid = t >> 6, lane = t & 63;
    __shared__ float4 ys4[Hq / 4];
    ys4[t] = ((const float4*)(y + b * Hq))[t];
    __syncthreads();
    float4 y0 = ys4[lane], y1 = ys4[lane + 64], y2 = ys4[lane + 128], y3 = ys4[lane + 192];
    int h0 = blockIdx.x * 16 + wid * 4;
#pragma unroll
    for (int r = 0; r < 4; ++r) {
        int h = h0 + r;
        const float4* wrow = (const float4*)(Wv + (size_t)h * Hq);
        float4 v0 = wrow[lane], v1 = wrow[lane + 64], v2 = wrow[lane + 128], v3 = wrow[lane + 192];
        float d = v0.x * y0.x + v0.y * y0.y + v0.z * y0.z + v0.w * y0.w
                + v1.x * y1.x + v1.y * y1.y + v1.z * y1.z + v1.w * y1.w
                + v2.x * y2.x + v2.y * y2.y + v2.z * y2.z + v2.w * y2.w
                + v3.x * y3.x + v3.y * y3.y + v3.z * y3.z + v3.w * y3.w;
        d = waveReduceSum(d);
        if (lane == 0) ctx[b * Hq + h] = d + bv[h];
    }
}

extern "C" void kernel_launch(void* const* d_in, const int* in_sizes, int n_in,
                              void* d_out, int out_size, void* d_ws, size_t ws_size,
                              hipStream_t stream) {
    const float* hidden = (const float*)d_in[0];
    const float* sqi    = (const float*)d_in[1];
    const float* pos    = (const float*)d_in[2];
    const float* Wq     = (const float*)d_in[3];
    const float* bq     = (const float*)d_in[4];
    const float* Wk     = (const float*)d_in[5];
    // bk (d_in[6]) shifts every score in a row equally -> cancels in softmax
    const float* Wv     = (const float*)d_in[7];
    const float* bv     = (const float*)d_in[8];

    float* out  = (float*)d_out;
    float* ctx  = out;                    // [B,H]
    float* attn = out + Bq * Hq;          // [B,S,S]

    // workspace layout (floats)
    float* ws       = (float*)d_ws;
    float* wq_eff   = ws;                 // 1024
    float* y        = ws + 1024;          // 8192  (zeroed region ends: 9216)
    float* ext      = ws + 9216;          // 16 (min[8], max[8])
    float* cb       = ws + 9232;          // 1
    float* a_arr    = ws + 9248;          // 16384
    float* rinv_arr = ws + 25632;         // 16384

    (void)hipMemsetAsync(ws, 0, 9216 * sizeof(float), stream);   // wq_eff + y

    k_prep  <<<265, 256, 0, stream>>>(Wq, Wk, bq, sqi, wq_eff, cb, ext);
    k_a     <<<dim3(Sq / 4, Bq), 256, 0, stream>>>(hidden, pos, wq_eff, cb,
                                                   sqi, ext, a_arr, rinv_arr);
    k_attn_w<<<dim3(Sq / QT, Bq), 256, 0, stream>>>(sqi, a_arr, rinv_arr, ext, attn);
    k_yw    <<<dim3(64, Bq), 256, 0, stream>>>(hidden, pos, sqi, a_arr,
                                               rinv_arr, ext, y);
    k_ctx   <<<dim3(Hq / 16, Bq), 256, 0, stream>>>(Wv, bv, y, ctx);
}

// Round 12
// 248.464 us; speedup vs baseline: 1.2382x; 1.0078x over previous
//
#include <hip/hip_runtime.h>
#include <math.h>

#define Bq 8
#define Sq 2048
#define Hq 1024
#define QT 16          // attn rows per block in k_attn_w (4 waves x 4 rows)
#define INV_SQRT_H (1.0f / 32.0f)

typedef float f32x4 __attribute__((ext_vector_type(4)));

__device__ __forceinline__ float waveReduceSum(float v) {
#pragma unroll
    for (int off = 32; off > 0; off >>= 1) v += __shfl_xor(v, off, 64);
    return v;
}

// branchless exact row max of a*sqi over the batch row (sqi in [smin,smax])
__device__ __forceinline__ float rowMax(float aa, float smin, float smax) {
    return fmaxf(aa * smax, aa * smin);
}

// ---------------------------------------------------------------------------
// prep: blocks 0..255  -> wq_eff[h] = sum_o Wq[o,h]*Wk[o]  (atomic o-chunks)
//       block  256     -> cb = (bq . Wk)/sqrt(H)
//       blocks 257..264-> per-batch min/max of sqi
// ---------------------------------------------------------------------------
__global__ void k_prep(const float* __restrict__ Wq, const float* __restrict__ Wk,
                       const float* __restrict__ bq, const float* __restrict__ sqi,
                       float* __restrict__ wq_eff, float* __restrict__ cb,
                       float* __restrict__ ext) {
    int bid = blockIdx.x, t = threadIdx.x;
    int wid = t >> 6, lane = t & 63;
    if (bid < 256) {
        int hc = bid & 3, oc = bid >> 2;       // 4 h-chunks x 64 o-chunks
        int h = hc * 256 + t, o0 = oc * 16;
        float acc = 0.f;
#pragma unroll
        for (int o = 0; o < 16; ++o)
            acc += Wq[(size_t)(o0 + o) * Hq + h] * Wk[o0 + o];
        atomicAdd(&wq_eff[h], acc);
    } else if (bid == 256) {
        float acc = 0.f;
#pragma unroll
        for (int j = 0; j < 4; ++j) acc += bq[t * 4 + j] * Wk[t * 4 + j];
        acc = waveReduceSum(acc);
        __shared__ float red[4];
        if (lane == 0) red[wid] = acc;
        __syncthreads();
        if (t == 0) *cb = (red[0] + red[1] + red[2] + red[3]) * INV_SQRT_H;
    } else {
        int b = bid - 257;
        float mn = 1e30f, mx = -1e30f;
        for (int j = t; j < Sq; j += 256) {
            float v = sqi[b * Sq + j];
            mn = fminf(mn, v);
            mx = fmaxf(mx, v);
        }
#pragma unroll
        for (int off = 32; off > 0; off >>= 1) {
            mn = fminf(mn, __shfl_xor(mn, off, 64));
            mx = fmaxf(mx, __shfl_xor(mx, off, 64));
        }
        __shared__ float smn[4], smx[4];
        if (lane == 0) { smn[wid] = mn; smx[wid] = mx; }
        __syncthreads();
        if (t == 0) {
            ext[b]      = fminf(fminf(smn[0], smn[1]), fminf(smn[2], smn[3]));
            ext[Bq + b] = fmaxf(fmaxf(smx[0], smx[1]), fmaxf(smx[2], smx[3]));
        }
    }
}

// a[b,q] = ((hid+pos).wq_eff)/32 + cb ;  rinv[b,q] = 1/sum_kk exp(a*sqi-m)
// wave per row, 4 rows/block, 4096 blocks
__global__ void __launch_bounds__(256) k_a(
        const float* __restrict__ hidden, const float* __restrict__ pos,
        const float* __restrict__ wq_eff, const float* __restrict__ cbp,
        const float* __restrict__ sqi, const float* __restrict__ ext,
        float* __restrict__ a_arr, float* __restrict__ rinv_arr) {
    int b = blockIdx.y, t = threadIdx.x;
    int wid = t >> 6, lane = t & 63;
    __shared__ float sqi_s[Sq];
    {
        const float4* sp = (const float4*)(sqi + b * Sq);
        float4* ds = (float4*)sqi_s;
        ds[t]       = sp[t];
        ds[256 + t] = sp[256 + t];
    }
    float smin = ext[b], smax = ext[Bq + b];
    float cbv = *cbp;

    int q = blockIdx.x * 4 + wid;
    const float4* hp = (const float4*)(hidden + (size_t)(b * Sq + q) * Hq);
    const float4* pp = (const float4*)(pos + (size_t)q * Hq);
    const float4* wp = (const float4*)wq_eff;
    float d = 0.f;
#pragma unroll
    for (int seg = 0; seg < 4; ++seg) {
        float4 h = hp[lane + 64 * seg];
        float4 p = pp[lane + 64 * seg];
        float4 w = wp[lane + 64 * seg];
        d += (h.x + p.x) * w.x + (h.y + p.y) * w.y +
             (h.z + p.z) * w.z + (h.w + p.w) * w.w;
    }
    d = waveReduceSum(d);
    float aa = d * INV_SQRT_H + cbv;       // all lanes hold aa after reduce
    float m = rowMax(aa, smin, smax);
    __syncthreads();                        // sqi_s ready

    const float4* ss = (const float4*)sqi_s;
    float s = 0.f;
#pragma unroll
    for (int c = 0; c < 8; ++c) {
        float4 sv = ss[lane + 64 * c];
        s += __expf(aa * sv.x - m) + __expf(aa * sv.y - m)
           + __expf(aa * sv.z - m) + __expf(aa * sv.w - m);
    }
    s = waveReduceSum(s);
    if (lane == 0) {
        a_arr[b * Sq + q]    = aa;
        rinv_arr[b * Sq + q] = 1.0f / s;
    }
}

// attn[b,q,:] = exp(a*sqi - m) * rinv  -- pure streaming write, no tail.
__global__ void __launch_bounds__(256) k_attn_w(
        const float* __restrict__ sqi, const float* __restrict__ a_arr,
        const float* __restrict__ rinv_arr, const float* __restrict__ ext,
        float* __restrict__ attn) {
    int b = blockIdx.y, qt = blockIdx.x, t = threadIdx.x;
    int wid = t >> 6, lane = t & 63;
    __shared__ float sqi_s[Sq];
    {
        const float4* sp = (const float4*)(sqi + b * Sq);
        float4* ds = (float4*)sqi_s;
        ds[t]       = sp[t];
        ds[256 + t] = sp[256 + t];
    }
    float smin = ext[b], smax = ext[Bq + b];
    __syncthreads();

    const float4* ss = (const float4*)sqi_s;
    int q0 = qt * QT + wid * (QT / 4);
    float av[QT / 4], rv[QT / 4];
#pragma unroll
    for (int r = 0; r < QT / 4; ++r) {      // hoist row scalars (broadcast loads)
        av[r] = a_arr[b * Sq + q0 + r];
        rv[r] = rinv_arr[b * Sq + q0 + r];
    }
#pragma unroll
    for (int r = 0; r < QT / 4; ++r) {
        float aa = av[r];
        float rvv = rv[r];
        float m = rowMax(aa, smin, smax);
        f32x4* orow = (f32x4*)(attn + (size_t)(b * Sq + q0 + r) * Sq);
#pragma unroll
        for (int c = 0; c < 8; ++c) {
            float4 sv = ss[lane + 64 * c];
            f32x4 p;
            p.x = __expf(aa * sv.x - m) * rvv;
            p.y = __expf(aa * sv.y - m) * rvv;
            p.z = __expf(aa * sv.z - m) * rvv;
            p.w = __expf(aa * sv.w - m) * rvv;
            __builtin_nontemporal_store(p, &orow[lane + 64 * c]);
        }
    }
}

// Fused column-weights + y accumulation.
// Block (kc,b) owns 32 columns: wv[c] = (1/S) sum_q rinv[q]*exp(a[q]*sqi[c]-m[q])
// computed locally (bitwise-same expf formula as k_attn_w), then
// y[b,h] += sum_{kk in tile} wv * (hidden[b,kk,h] + pos[kk,h]).
__global__ void __launch_bounds__(256) k_yw(
        const float* __restrict__ hidden, const float* __restrict__ pos,
        const float* __restrict__ sqi, const float* __restrict__ a_arr,
        const float* __restrict__ rinv_arr, const float* __restrict__ ext,
        float* __restrict__ y) {
    int b = blockIdx.y, kc = blockIdx.x, t = threadIdx.x;
    __shared__ float a_s[Sq], r_s[Sq];
    __shared__ float partial[32][9];        // 9 (coprime 32) -> conflict-free
    __shared__ float wv_s[32];
    {
        const float4* ap = (const float4*)(a_arr + b * Sq);
        const float4* rp = (const float4*)(rinv_arr + b * Sq);
        float4* as4 = (float4*)a_s;
        float4* rs4 = (float4*)r_s;
        as4[t] = ap[t];  as4[256 + t] = ap[256 + t];
        rs4[t] = rp[t];  rs4[256 + t] = rp[256 + t];
    }
    float smin = ext[b], smax = ext[Bq + b];
    int c = t & 31, chunk = t >> 5;        // 32 cols x 8 q-chunks of 256
    int kk0 = kc * 32;
    float sk = sqi[b * Sq + kk0 + c];
    __syncthreads();

    float acc = 0.f;
    int j0 = chunk * 256;
#pragma unroll 8
    for (int j = 0; j < 256; ++j) {
        float aa = a_s[j0 + j];            // 2-addr broadcast per wave (free)
        float m = rowMax(aa, smin, smax);
        acc += r_s[j0 + j] * __expf(aa * sk - m);
    }
    partial[c][chunk] = acc;
    __syncthreads();
    if (t < 32) {
        float w = 0.f;
#pragma unroll
        for (int u = 0; u < 8; ++u) w += partial[t][u];
        wv_s[t] = w * (1.0f / Sq);
    }
    __syncthreads();

    float4 accv = {0, 0, 0, 0};
#pragma unroll 8
    for (int i = 0; i < 32; ++i) {
        int kk = kk0 + i;
        float wv = wv_s[i];
        float4 hv = ((const float4*)(hidden + ((size_t)(b * Sq + kk)) * Hq))[t];
        float4 pv = ((const float4*)(pos + (size_t)kk * Hq))[t];
        accv.x += wv * (hv.x + pv.x);
        accv.y += wv * (hv.y + pv.y);
        accv.z += wv * (hv.z + pv.z);
        accv.w += wv * (hv.w + pv.w);
    }
    atomicAdd(&y[b * Hq + t * 4 + 0], accv.x);
    atomicAdd(&y[b * Hq + t * 4 + 1], accv.y);
    atomicAdd(&y[b * Hq + t * 4 + 2], accv.z);
    atomicAdd(&y[b * Hq + t * 4 + 3], accv.w);
}

// ctx[b,h] = Wv[h,:] . y[b,:] + bv[h]  -- wave per 4 rows, direct store
__global__ void k_ctx(const float* __restrict__ Wv, const float* __restrict__ bv,
                      const float* __restrict__ y, float* __restrict__ ctx) {
    int b = blockIdx.y, t = threadIdx.x;
    int wid = t >> 6, lane = t & 63;
    __shared__ float4 ys4[Hq / 4];
    ys4[t] = ((const float4*)(y + b * Hq))[t];
    __syncthreads();
    float4 y0 = ys4[lane], y1 = ys4[lane + 64], y2 = ys4[lane + 128], y3 = ys4[lane + 192];
    int h0 = blockIdx.x * 16 + wid * 4;
#pragma unroll
    for (int r = 0; r < 4; ++r) {
        int h = h0 + r;
        const float4* wrow = (const float4*)(Wv + (size_t)h * Hq);
        float4 v0 = wrow[lane], v1 = wrow[lane + 64], v2 = wrow[lane + 128], v3 = wrow[lane + 192];
        float d = v0.x * y0.x + v0.y * y0.y + v0.z * y0.z + v0.w * y0.w
                + v1.x * y1.x + v1.y * y1.y + v1.z * y1.z + v1.w * y1.w
                + v2.x * y2.x + v2.y * y2.y + v2.z * y2.z + v2.w * y2.w
                + v3.x * y3.x + v3.y * y3.y + v3.z * y3.z + v3.w * y3.w;
        d = waveReduceSum(d);
        if (lane == 0) ctx[b * Hq + h] = d + bv[h];
    }
}

extern "C" void kernel_launch(void* const* d_in, const int* in_sizes, int n_in,
                              void* d_out, int out_size, void* d_ws, size_t ws_size,
                              hipStream_t stream) {
    const float* hidden = (const float*)d_in[0];
    const float* sqi    = (const float*)d_in[1];
    const float* pos    = (const float*)d_in[2];
    const float* Wq     = (const float*)d_in[3];
    const float* bq     = (const float*)d_in[4];
    const float* Wk     = (const float*)d_in[5];
    // bk (d_in[6]) shifts every score in a row equally -> cancels in softmax
    const float* Wv     = (const float*)d_in[7];
    const float* bv     = (const float*)d_in[8];

    float* out  = (float*)d_out;
    float* ctx  = out;                    // [B,H]
    float* attn = out + Bq * Hq;          // [B,S,S]

    // workspace layout (floats)
    float* ws       = (float*)d_ws;
    float* wq_eff   = ws;                 // 1024
    float* y        = ws + 1024;          // 8192  (zeroed region ends: 9216)
    float* ext      = ws + 9216;          // 16 (min[8], max[8])
    float* cb       = ws + 9232;          // 1
    float* a_arr    = ws + 9248;          // 16384
    float* rinv_arr = ws + 25632;         // 16384

    (void)hipMemsetAsync(ws, 0, 9216 * sizeof(float), stream);   // wq_eff + y

    k_prep  <<<265, 256, 0, stream>>>(Wq, Wk, bq, sqi, wq_eff, cb, ext);
    k_a     <<<dim3(Sq / 4, Bq), 256, 0, stream>>>(hidden, pos, wq_eff, cb,
                                                   sqi, ext, a_arr, rinv_arr);
    // k_yw right after k_a: its 64 MB hidden re-read is still L3-resident.
    k_yw    <<<dim3(64, Bq), 256, 0, stream>>>(hidden, pos, sqi, a_arr,
                                               rinv_arr, ext, y);
    k_ctx   <<<dim3(Hq / 16, Bq), 256, 0, stream>>>(Wv, bv, y, ctx);
    // attn streaming write last so it cannot evict hidden before k_yw reads it.
    k_attn_w<<<dim3(Sq / QT, Bq), 256, 0, stream>>>(sqi, a_arr, rinv_arr, ext, attn);
}